// Round 9
// baseline (54.747 us; speedup 1.0000x reference)
//
#include <hip/hip_runtime.h>
#include <hip/hip_bf16.h>
#include <math.h>

// out[i,j] = max( (x[i]·W[j]) / (|x_i| |W_j|), 1e-10 ) + b[j]
// B=65536, IN=OUT=256, fp32 in/out.
// Round 9: asymmetric wave roles to overlap compute with the x drain.
//   waves 4-7: x burst at t=0 -> raw s_barrier (loads stay in flight)
//   waves 0-3: stage all W (bf16, swizzled) + winv + bias, then x burst
//   K-loop: per-slot x conversion (progressive vmcnt) -> MFMA of slot k
//   overlaps HBM drain of slots k+1.. ; slots 6-7 issued mid-loop (VGPR cap).
// vmcnt is per-wave, so W staging no longer serializes behind the x drain
// (R7's flaw), while x-first-chip-wide (R7's traffic win) is preserved.

using bf16x8 = __attribute__((ext_vector_type(8))) short;   // 8 bf16 = 4 VGPRs
using f32x4  = __attribute__((ext_vector_type(4))) float;

#define W_LDS_BYTES 131072                        // 256 rows * 512 B (bf16, swizzled)
#define LDS_BYTES   (W_LDS_BYTES + 1024 + 1024)   // + winv[256] + b[256]
#define EPS 1e-10f

__device__ __forceinline__ short f2bf(float f) {
    __bf16 h = (__bf16)f;                         // RNE; pairs fuse to v_cvt_pk_bf16_f32
    return __builtin_bit_cast(short, h);
}

__global__ __launch_bounds__(512, 2) void ffn_cosnorm_kernel(
    const float* __restrict__ x, const float* __restrict__ W,
    const float* __restrict__ b, float* __restrict__ out)
{
    extern __shared__ char smem[];
    float* winv = (float*)(smem + W_LDS_BYTES);           // [256] 1/|W_j|
    float* blds = (float*)(smem + W_LDS_BYTES + 1024);    // [256] bias

    const int t    = threadIdx.x;
    const int lane = t & 63;
    const int wave = t >> 6;                  // 0..7
    const int r16  = lane & 15;               // x row within M-tile (= D col, in-lane)
    const int kg   = lane >> 4;               // 0..3 : K-slice of 8
    const int rxor = (r16 & 7) << 4;          // W-frag read swizzle
    const size_t rowb = (size_t)blockIdx.x * 256 + (size_t)wave * 32;

    const float* xp0 = x + (rowb + r16) * 256 + kg * 8;   // M-tile 0 row
    const float* xp1 = xp0 + 16 * 256;                     // M-tile 1 row

    // ---------------- W staging: waves 0-3 only (their vmcnt queue = W only) ----------------
    if (wave < 4) {
        const float* wr = W + (size_t)t * 256;  // thread t (0..255) owns W row t
        const int rx = (t & 7) << 4;            // swizzle term
        float ss = 0.f;
        #pragma unroll
        for (int i = 0; i < 32; ++i) {          // 32 groups of 8 floats = full row
            float4 a = *(const float4*)(wr + i * 8);
            float4 c = *(const float4*)(wr + i * 8 + 4);
            ss = fmaf(a.x, a.x, ss); ss = fmaf(a.y, a.y, ss);
            ss = fmaf(a.z, a.z, ss); ss = fmaf(a.w, a.w, ss);
            ss = fmaf(c.x, c.x, ss); ss = fmaf(c.y, c.y, ss);
            ss = fmaf(c.z, c.z, ss); ss = fmaf(c.w, c.w, ss);
            bf16x8 v;
            v[0] = f2bf(a.x); v[1] = f2bf(a.y); v[2] = f2bf(a.z); v[3] = f2bf(a.w);
            v[4] = f2bf(c.x); v[5] = f2bf(c.y); v[6] = f2bf(c.z); v[7] = f2bf(c.w);
            const int off = t * 512 + ((i * 16) ^ rx);
            *(bf16x8*)(smem + off) = v;         // ds_write_b128 (8-way, tolerated)
        }
        winv[t] = 1.0f / sqrtf(ss);             // full-row sumsq in-thread
        blds[t] = b[t];
    }

    // ---------------- x burst: slots 0-5 (96 VGPR). x-waves issue this at t=0 ----------------
    float4 f0a[8], f0b[8], f1a[8], f1b[8];
    #pragma unroll
    for (int s = 0; s < 6; ++s) {
        f0a[s] = *(const float4*)(xp0 + s * 32);
        f0b[s] = *(const float4*)(xp0 + s * 32 + 4);
        f1a[s] = *(const float4*)(xp1 + s * 32);
        f1b[s] = *(const float4*)(xp1 + s * 32 + 4);
    }

    // ---------------- raw barrier: does NOT drain vmcnt (x stays in flight) ----------------
    if (wave < 4) {
        asm volatile("s_waitcnt lgkmcnt(0)" ::: "memory");  // W ds_writes visible
    }
    __builtin_amdgcn_s_barrier();
    __builtin_amdgcn_sched_barrier(0);        // pin: burst above, ds_reads below

    // ---------------- K-loop: per-slot convert (progressive vmcnt) + MFMA ----------------
    f32x4 acc0[16], acc1[16];
    #pragma unroll
    for (int n = 0; n < 16; ++n) {
        acc0[n] = f32x4{0.f, 0.f, 0.f, 0.f};
        acc1[n] = f32x4{0.f, 0.f, 0.f, 0.f};
    }
    float ss0 = 0.f, ss1 = 0.f;

    #pragma unroll
    for (int k0 = 0; k0 < 8; ++k0) {          // K = 8 steps of 32
        if (k0 == 2) {                        // late-issue slot 6 (regs freed by now)
            f0a[6] = *(const float4*)(xp0 + 6 * 32);
            f0b[6] = *(const float4*)(xp0 + 6 * 32 + 4);
            f1a[6] = *(const float4*)(xp1 + 6 * 32);
            f1b[6] = *(const float4*)(xp1 + 6 * 32 + 4);
        }
        if (k0 == 3) {                        // late-issue slot 7
            f0a[7] = *(const float4*)(xp0 + 7 * 32);
            f0b[7] = *(const float4*)(xp0 + 7 * 32 + 4);
            f1a[7] = *(const float4*)(xp1 + 7 * 32);
            f1b[7] = *(const float4*)(xp1 + 7 * 32 + 4);
        }
        // convert slot k0 (compiler waits only for this slot's loads)
        float4 ca = f0a[k0], cb = f0b[k0];
        float4 da = f1a[k0], db = f1b[k0];
        bf16x8 a0, a1;
        a0[0] = f2bf(ca.x); a0[1] = f2bf(ca.y); a0[2] = f2bf(ca.z); a0[3] = f2bf(ca.w);
        a0[4] = f2bf(cb.x); a0[5] = f2bf(cb.y); a0[6] = f2bf(cb.z); a0[7] = f2bf(cb.w);
        a1[0] = f2bf(da.x); a1[1] = f2bf(da.y); a1[2] = f2bf(da.z); a1[3] = f2bf(da.w);
        a1[4] = f2bf(db.x); a1[5] = f2bf(db.y); a1[6] = f2bf(db.z); a1[7] = f2bf(db.w);
        ss0 = fmaf(ca.x, ca.x, ss0); ss0 = fmaf(ca.y, ca.y, ss0);
        ss0 = fmaf(ca.z, ca.z, ss0); ss0 = fmaf(ca.w, ca.w, ss0);
        ss0 = fmaf(cb.x, cb.x, ss0); ss0 = fmaf(cb.y, cb.y, ss0);
        ss0 = fmaf(cb.z, cb.z, ss0); ss0 = fmaf(cb.w, cb.w, ss0);
        ss1 = fmaf(da.x, da.x, ss1); ss1 = fmaf(da.y, da.y, ss1);
        ss1 = fmaf(da.z, da.z, ss1); ss1 = fmaf(da.w, da.w, ss1);
        ss1 = fmaf(db.x, db.x, ss1); ss1 = fmaf(db.y, db.y, ss1);
        ss1 = fmaf(db.z, db.z, ss1); ss1 = fmaf(db.w, db.w, ss1);

        const int cswz = (k0 * 64 + kg * 16) ^ rxor;
        #pragma unroll
        for (int n = 0; n < 16; ++n) {
            const int addr = (n * 16 + r16) * 512 + cswz;
            bf16x8 wfr = *(const bf16x8*)(smem + addr);   // ds_read_b128 -> 2 MFMAs
            acc0[n] = __builtin_amdgcn_mfma_f32_16x16x32_bf16(wfr, a0, acc0[n], 0, 0, 0);
            acc1[n] = __builtin_amdgcn_mfma_f32_16x16x32_bf16(wfr, a1, acc1[n], 0, 0, 0);
        }
    }

    // ---------------- x_len: butterfly over K-groups; in-lane result ----------------
    ss0 += __shfl_xor(ss0, 16); ss0 += __shfl_xor(ss0, 32);
    ss1 += __shfl_xor(ss1, 16); ss1 += __shfl_xor(ss1, 32);
    const float inv0 = 1.0f / sqrtf(ss0);     // 1/|x_row(r16)|
    const float inv1 = 1.0f / sqrtf(ss1);     // 1/|x_row(r16+16)|

    // ---------------- epilogue: scale, clamp, +bias, burst float4 stores ----------------
    const int jb = kg * 4;
    float* op0 = out + (rowb + r16) * 256;
    float* op1 = op0 + (size_t)16 * 256;
    #pragma unroll
    for (int n = 0; n < 16; ++n) {
        float4 wv = *(const float4*)(winv + n * 16 + jb);
        float4 bv = *(const float4*)(blds + n * 16 + jb);
        f32x4 o0, o1;
        o0[0] = fmaxf(acc0[n][0] * (inv0 * wv.x), EPS) + bv.x;
        o0[1] = fmaxf(acc0[n][1] * (inv0 * wv.y), EPS) + bv.y;
        o0[2] = fmaxf(acc0[n][2] * (inv0 * wv.z), EPS) + bv.z;
        o0[3] = fmaxf(acc0[n][3] * (inv0 * wv.w), EPS) + bv.w;
        o1[0] = fmaxf(acc1[n][0] * (inv1 * wv.x), EPS) + bv.x;
        o1[1] = fmaxf(acc1[n][1] * (inv1 * wv.y), EPS) + bv.y;
        o1[2] = fmaxf(acc1[n][2] * (inv1 * wv.z), EPS) + bv.z;
        o1[3] = fmaxf(acc1[n][3] * (inv1 * wv.w), EPS) + bv.w;
        *(f32x4*)(op0 + n * 16 + jb) = o0;    // adjacent n pairs complete 128B lines
        *(f32x4*)(op1 + n * 16 + jb) = o1;
    }
}

extern "C" void kernel_launch(void* const* d_in, const int* in_sizes, int n_in,
                              void* d_out, int out_size, void* d_ws, size_t ws_size,
                              hipStream_t stream) {
    const float* x = (const float*)d_in[0];
    const float* W = (const float*)d_in[1];
    const float* b = (const float*)d_in[2];
    float* out = (float*)d_out;

    hipFuncSetAttribute((const void*)ffn_cosnorm_kernel,
                        hipFuncAttributeMaxDynamicSharedMemorySize, LDS_BYTES);
    ffn_cosnorm_kernel<<<dim3(256), dim3(512), LDS_BYTES, stream>>>(x, W, b, out);
}

// Round 10
// 36.341 us; speedup vs baseline: 1.5065x; 1.5065x over previous
//
#include <hip/hip_runtime.h>
#include <hip/hip_bf16.h>
#include <math.h>

// out[i,j] = max( (x[i]·W[j]) / (|x_i| |W_j|), 1e-10 ) + b[j]
// B=65536, IN=OUT=256, fp32 in/out.
// Round 10: R7 (best: x burst at t=0, W prologue after, full-register x,
// pure-LDS compute) with the loop nest INVERTED: n-outer / K-inner.
// acc shrinks 128->8 VGPRs and each col-window's stores issue immediately
// after its 16 MFMAs -> stores stream through the compute phase instead of
// bursting at the kernel tail (R7's exposed ~11us store drain).

using bf16x8 = __attribute__((ext_vector_type(8))) short;   // 8 bf16 = 4 VGPRs
using f32x4  = __attribute__((ext_vector_type(4))) float;

#define W_LDS_BYTES 131072                        // 256 rows * 512 B (bf16, swizzled)
#define LDS_BYTES   (W_LDS_BYTES + 1024 + 1024)   // + winv[256] + b[256]
#define EPS 1e-10f

__device__ __forceinline__ short f2bf(float f) {
    __bf16 h = (__bf16)f;                         // RNE; pairs fuse to v_cvt_pk_bf16_f32
    return __builtin_bit_cast(short, h);
}

__global__ __launch_bounds__(512, 2) void ffn_cosnorm_kernel(
    const float* __restrict__ x, const float* __restrict__ W,
    const float* __restrict__ b, float* __restrict__ out)
{
    extern __shared__ char smem[];
    float* winv = (float*)(smem + W_LDS_BYTES);           // [256] 1/|W_j|
    float* blds = (float*)(smem + W_LDS_BYTES + 1024);    // [256] bias

    const int t    = threadIdx.x;
    const int lane = t & 63;
    const int wave = t >> 6;                  // 0..7
    const int r16  = lane & 15;               // x row within M-tile (= D col, in-lane)
    const int kg   = lane >> 4;               // 0..3 : K-slice of 8
    const int rxor = (r16 & 7) << 4;          // W-frag read swizzle
    const size_t rowb = (size_t)blockIdx.x * 256 + (size_t)wave * 32;

    const float* xp0 = x + (rowb + r16) * 256 + kg * 8;   // M-tile 0 row
    const float* xp1 = xp0 + 16 * 256;                     // M-tile 1 row

    // ---- x burst FIRST (R7 order is the traffic optimum: FETCH 36/WRITE 72 MB) ----
    float4 f0a[8], f0b[8], f1a[8], f1b[8];    // 128 VGPR, transient
    #pragma unroll
    for (int s = 0; s < 8; ++s) {
        f0a[s] = *(const float4*)(xp0 + s * 32);
        f0b[s] = *(const float4*)(xp0 + s * 32 + 4);
        f1a[s] = *(const float4*)(xp1 + s * 32);
        f1b[s] = *(const float4*)(xp1 + s * 32 + 4);
    }

    // ---------------- prologue: stage W (fp32->bf16, XOR-swizzled) + w_len ----------------
    {
        const int wrow = t >> 1;              // 0..255 (W row = output col j)
        const int half = t & 1;               // which 128-col half
        const float* wr = W + (size_t)wrow * 256 + half * 128;
        const int rx = (wrow & 7) << 4;       // swizzle term
        float ss = 0.f;
        #pragma unroll
        for (int i = 0; i < 16; ++i) {        // 16 groups of 8 floats
            float4 a = *(const float4*)(wr + i * 8);
            float4 c = *(const float4*)(wr + i * 8 + 4);
            ss = fmaf(a.x, a.x, ss); ss = fmaf(a.y, a.y, ss);
            ss = fmaf(a.z, a.z, ss); ss = fmaf(a.w, a.w, ss);
            ss = fmaf(c.x, c.x, ss); ss = fmaf(c.y, c.y, ss);
            ss = fmaf(c.z, c.z, ss); ss = fmaf(c.w, c.w, ss);
            bf16x8 v;
            v[0] = f2bf(a.x); v[1] = f2bf(a.y); v[2] = f2bf(a.z); v[3] = f2bf(a.w);
            v[4] = f2bf(c.x); v[5] = f2bf(c.y); v[6] = f2bf(c.z); v[7] = f2bf(c.w);
            const int off = wrow * 512 + ((half * 256 + i * 16) ^ rx);
            *(bf16x8*)(smem + off) = v;       // ds_write_b128
        }
        ss += __shfl_xor(ss, 1);              // combine the two halves
        if (!half) winv[wrow] = 1.0f / sqrtf(ss);
        if (t < 256) blds[t] = b[t];
    }

    // ---- convert x -> bf16 fragments + fp32 sum-of-squares ----
    bf16x8 xb0[8], xb1[8];                    // 64 VGPR persistent
    float ss0 = 0.f, ss1 = 0.f;
    #pragma unroll
    for (int s = 0; s < 8; ++s) {
        float4 a = f0a[s], c = f0b[s];
        bf16x8 v;
        v[0] = f2bf(a.x); v[1] = f2bf(a.y); v[2] = f2bf(a.z); v[3] = f2bf(a.w);
        v[4] = f2bf(c.x); v[5] = f2bf(c.y); v[6] = f2bf(c.z); v[7] = f2bf(c.w);
        xb0[s] = v;
        ss0 = fmaf(a.x, a.x, ss0); ss0 = fmaf(a.y, a.y, ss0);
        ss0 = fmaf(a.z, a.z, ss0); ss0 = fmaf(a.w, a.w, ss0);
        ss0 = fmaf(c.x, c.x, ss0); ss0 = fmaf(c.y, c.y, ss0);
        ss0 = fmaf(c.z, c.z, ss0); ss0 = fmaf(c.w, c.w, ss0);
        float4 a1 = f1a[s], c1 = f1b[s];
        bf16x8 w1;
        w1[0] = f2bf(a1.x); w1[1] = f2bf(a1.y); w1[2] = f2bf(a1.z); w1[3] = f2bf(a1.w);
        w1[4] = f2bf(c1.x); w1[5] = f2bf(c1.y); w1[6] = f2bf(c1.z); w1[7] = f2bf(c1.w);
        xb1[s] = w1;
        ss1 = fmaf(a1.x, a1.x, ss1); ss1 = fmaf(a1.y, a1.y, ss1);
        ss1 = fmaf(a1.z, a1.z, ss1); ss1 = fmaf(a1.w, a1.w, ss1);
        ss1 = fmaf(c1.x, c1.x, ss1); ss1 = fmaf(c1.y, c1.y, ss1);
        ss1 = fmaf(c1.w, c1.w, ss1); ss1 = fmaf(c1.z, c1.z, ss1);
    }

    // ---- x_len: butterfly over K-groups; in-lane result (before the barrier) ----
    ss0 += __shfl_xor(ss0, 16); ss0 += __shfl_xor(ss0, 32);
    ss1 += __shfl_xor(ss1, 16); ss1 += __shfl_xor(ss1, 32);
    const float inv0 = 1.0f / sqrtf(ss0);     // 1/|x_row(r16)|
    const float inv1 = 1.0f / sqrtf(ss1);     // 1/|x_row(r16+16)|

    __syncthreads();                          // W staged; only barrier in the kernel

    // ---------------- n-outer loop: compute one 16-col window, store it, repeat ----
    const int jb = kg * 4;
    float* op0 = out + (rowb + r16) * 256;
    float* op1 = op0 + (size_t)16 * 256;

    #pragma unroll
    for (int n = 0; n < 16; ++n) {
        f32x4 acc0 = f32x4{0.f, 0.f, 0.f, 0.f};
        f32x4 acc1 = f32x4{0.f, 0.f, 0.f, 0.f};
        #pragma unroll
        for (int k0 = 0; k0 < 8; ++k0) {
            const int addr = (n * 16 + r16) * 512 + ((k0 * 64 + kg * 16) ^ rxor);
            bf16x8 wfr = *(const bf16x8*)(smem + addr);   // ds_read_b128 -> 2 MFMAs
            acc0 = __builtin_amdgcn_mfma_f32_16x16x32_bf16(wfr, xb0[k0], acc0, 0, 0, 0);
            acc1 = __builtin_amdgcn_mfma_f32_16x16x32_bf16(wfr, xb1[k0], acc1, 0, 0, 0);
        }
        float4 wv = *(const float4*)(winv + n * 16 + jb);
        float4 bv = *(const float4*)(blds + n * 16 + jb);
        f32x4 o0, o1;
        o0[0] = fmaxf(acc0[0] * (inv0 * wv.x), EPS) + bv.x;
        o0[1] = fmaxf(acc0[1] * (inv0 * wv.y), EPS) + bv.y;
        o0[2] = fmaxf(acc0[2] * (inv0 * wv.z), EPS) + bv.z;
        o0[3] = fmaxf(acc0[3] * (inv0 * wv.w), EPS) + bv.w;
        o1[0] = fmaxf(acc1[0] * (inv1 * wv.x), EPS) + bv.x;
        o1[1] = fmaxf(acc1[1] * (inv1 * wv.y), EPS) + bv.y;
        o1[2] = fmaxf(acc1[2] * (inv1 * wv.z), EPS) + bv.z;
        o1[3] = fmaxf(acc1[3] * (inv1 * wv.w), EPS) + bv.w;
        *(f32x4*)(op0 + n * 16 + jb) = o0;    // stores stream through compute
        *(f32x4*)(op1 + n * 16 + jb) = o1;
        __builtin_amdgcn_sched_barrier(0);    // pin per-n interleave (no store sinking)
    }
}

extern "C" void kernel_launch(void* const* d_in, const int* in_sizes, int n_in,
                              void* d_out, int out_size, void* d_ws, size_t ws_size,
                              hipStream_t stream) {
    const float* x = (const float*)d_in[0];
    const float* W = (const float*)d_in[1];
    const float* b = (const float*)d_in[2];
    float* out = (float*)d_out;

    hipFuncSetAttribute((const void*)ffn_cosnorm_kernel,
                        hipFuncAttributeMaxDynamicSharedMemorySize, LDS_BYTES);
    ffn_cosnorm_kernel<<<dim3(256), dim3(512), LDS_BYTES, stream>>>(x, W, b, out);
}

// Round 11
// 34.626 us; speedup vs baseline: 1.5811x; 1.0495x over previous
//
#include <hip/hip_runtime.h>
#include <hip/hip_bf16.h>
#include <math.h>

// out[i,j] = max( (x[i]·W[j]) / (|x_i| |W_j|), 1e-10 ) + b[j]
// B=65536, IN=OUT=256, fp32 in/out.
// Round 11: R10 (x-first burst, W prologue, register-x, n-outer streamed
// stores) at DOUBLE occupancy: 1024 threads, 16 waves x 1 M-tile (16 rows).
// Per-wave regs halve (burst 64 + xb 32 + acc 4) -> 4 waves/SIMD instead of 2;
// waves draining x overlap waves computing/storing. Cost: each ds_read feeds
// 1 MFMA (2 MB/CU LDS reads ~10us < 17us memory stream -> hidden).

using bf16x8 = __attribute__((ext_vector_type(8))) short;   // 8 bf16 = 4 VGPRs
using f32x4  = __attribute__((ext_vector_type(4))) float;

#define W_LDS_BYTES 131072                        // 256 rows * 512 B (bf16, swizzled)
#define LDS_BYTES   (W_LDS_BYTES + 1024 + 1024)   // + winv[256] + b[256]
#define EPS 1e-10f

__device__ __forceinline__ short f2bf(float f) {
    __bf16 h = (__bf16)f;                         // RNE; pairs fuse to v_cvt_pk_bf16_f32
    return __builtin_bit_cast(short, h);
}

__global__ __launch_bounds__(1024, 4) void ffn_cosnorm_kernel(
    const float* __restrict__ x, const float* __restrict__ W,
    const float* __restrict__ b, float* __restrict__ out)
{
    extern __shared__ char smem[];
    float* winv = (float*)(smem + W_LDS_BYTES);           // [256] 1/|W_j|
    float* blds = (float*)(smem + W_LDS_BYTES + 1024);    // [256] bias

    const int t    = threadIdx.x;
    const int lane = t & 63;
    const int wave = t >> 6;                  // 0..15
    const int r16  = lane & 15;               // x row within M-tile (= D col, in-lane)
    const int kg   = lane >> 4;               // 0..3 : K-slice of 8
    const int rxor = (r16 & 7) << 4;          // W-frag read swizzle
    const size_t rowb = (size_t)blockIdx.x * 256 + (size_t)wave * 16;

    const float* xp = x + (rowb + r16) * 256 + kg * 8;

    // ---- x burst FIRST (x-first program order = the traffic optimum) ----
    float4 fa[8], fb[8];                      // 64 VGPR transient
    #pragma unroll
    for (int s = 0; s < 8; ++s) {
        fa[s] = *(const float4*)(xp + s * 32);
        fb[s] = *(const float4*)(xp + s * 32 + 4);
    }

    // ---------------- prologue: stage W (fp32->bf16, XOR-swizzled) + w_len ----------------
    {
        const int wrow = t >> 2;              // 0..255 W row (output col j)
        const int q    = t & 3;               // 64-float quarter of the row
        const float* wr = W + (size_t)wrow * 256 + q * 64;
        const int rx = (wrow & 7) << 4;       // swizzle term
        float ss = 0.f;
        #pragma unroll
        for (int i = 0; i < 8; ++i) {         // 8 groups of 8 floats
            float4 a = *(const float4*)(wr + i * 8);
            float4 c = *(const float4*)(wr + i * 8 + 4);
            ss = fmaf(a.x, a.x, ss); ss = fmaf(a.y, a.y, ss);
            ss = fmaf(a.z, a.z, ss); ss = fmaf(a.w, a.w, ss);
            ss = fmaf(c.x, c.x, ss); ss = fmaf(c.y, c.y, ss);
            ss = fmaf(c.z, c.z, ss); ss = fmaf(c.w, c.w, ss);
            bf16x8 v;
            v[0] = f2bf(a.x); v[1] = f2bf(a.y); v[2] = f2bf(a.z); v[3] = f2bf(a.w);
            v[4] = f2bf(c.x); v[5] = f2bf(c.y); v[6] = f2bf(c.z); v[7] = f2bf(c.w);
            const int off = wrow * 512 + ((q * 128 + i * 16) ^ rx);
            *(bf16x8*)(smem + off) = v;       // ds_write_b128
        }
        ss += __shfl_xor(ss, 1);              // combine the 4 quarters
        ss += __shfl_xor(ss, 2);
        if (q == 0) winv[wrow] = 1.0f / sqrtf(ss);
        if (t < 256) blds[t] = b[t];
    }

    // ---- convert x -> bf16 fragments + fp32 sum-of-squares ----
    bf16x8 xb[8];                             // 32 VGPR persistent
    float ssx = 0.f;
    #pragma unroll
    for (int s = 0; s < 8; ++s) {
        float4 a = fa[s], c = fb[s];
        bf16x8 v;
        v[0] = f2bf(a.x); v[1] = f2bf(a.y); v[2] = f2bf(a.z); v[3] = f2bf(a.w);
        v[4] = f2bf(c.x); v[5] = f2bf(c.y); v[6] = f2bf(c.z); v[7] = f2bf(c.w);
        xb[s] = v;
        ssx = fmaf(a.x, a.x, ssx); ssx = fmaf(a.y, a.y, ssx);
        ssx = fmaf(a.z, a.z, ssx); ssx = fmaf(a.w, a.w, ssx);
        ssx = fmaf(c.x, c.x, ssx); ssx = fmaf(c.y, c.y, ssx);
        ssx = fmaf(c.z, c.z, ssx); ssx = fmaf(c.w, c.w, ssx);
    }

    // ---- x_len: butterfly over K-groups; in-lane result (before the barrier) ----
    ssx += __shfl_xor(ssx, 16); ssx += __shfl_xor(ssx, 32);
    const float inv = 1.0f / sqrtf(ssx);      // 1/|x_row(r16)|

    __syncthreads();                          // W staged; only barrier in the kernel

    // ---------------- n-outer loop: compute one 16-col window, store it, repeat ----
    const int jb = kg * 4;
    float* op = out + (rowb + r16) * 256;

    #pragma unroll
    for (int n = 0; n < 16; ++n) {
        f32x4 acc = f32x4{0.f, 0.f, 0.f, 0.f};
        #pragma unroll
        for (int k0 = 0; k0 < 8; ++k0) {
            const int addr = (n * 16 + r16) * 512 + ((k0 * 64 + kg * 16) ^ rxor);
            bf16x8 wfr = *(const bf16x8*)(smem + addr);   // ds_read_b128
            acc = __builtin_amdgcn_mfma_f32_16x16x32_bf16(wfr, xb[k0], acc, 0, 0, 0);
        }
        float4 wv = *(const float4*)(winv + n * 16 + jb);
        float4 bv = *(const float4*)(blds + n * 16 + jb);
        f32x4 o;
        o[0] = fmaxf(acc[0] * (inv * wv.x), EPS) + bv.x;
        o[1] = fmaxf(acc[1] * (inv * wv.y), EPS) + bv.y;
        o[2] = fmaxf(acc[2] * (inv * wv.z), EPS) + bv.z;
        o[3] = fmaxf(acc[3] * (inv * wv.w), EPS) + bv.w;
        *(f32x4*)(op + n * 16 + jb) = o;      // stores stream through compute
        __builtin_amdgcn_sched_barrier(0);    // pin per-n interleave (no store sinking)
    }
}

extern "C" void kernel_launch(void* const* d_in, const int* in_sizes, int n_in,
                              void* d_out, int out_size, void* d_ws, size_t ws_size,
                              hipStream_t stream) {
    const float* x = (const float*)d_in[0];
    const float* W = (const float*)d_in[1];
    const float* b = (const float*)d_in[2];
    float* out = (float*)d_out;

    hipFuncSetAttribute((const void*)ffn_cosnorm_kernel,
                        hipFuncAttributeMaxDynamicSharedMemorySize, LDS_BYTES);
    ffn_cosnorm_kernel<<<dim3(256), dim3(1024), LDS_BYTES, stream>>>(x, W, b, out);
}